// Round 3
// baseline (4908.760 us; speedup 1.0000x reference)
//
#include <hip/hip_runtime.h>
#include <cmath>

#define B_   64
#define T_   512
#define IN_  256
#define H_   512
#define OUT_ 256
#define M_   (B_*T_)   // 32768 rows for the input-projection GEMM

typedef __bf16 bf16x4 __attribute__((ext_vector_type(4)));
typedef __bf16 bf16x8 __attribute__((ext_vector_type(8)));
typedef float  f32x4  __attribute__((ext_vector_type(4)));
typedef unsigned long long u64;

// Split fp32 into bf16 hi (truncated, exact) + bf16 lo (RN of remainder).
static __device__ __forceinline__ void split_f32(float x, __bf16 &hi, __bf16 &lo) {
    unsigned u  = __float_as_uint(x);
    unsigned hu = u & 0xffff0000u;
    hi = __builtin_bit_cast(__bf16, (unsigned short)(hu >> 16));
    lo = (__bf16)(x - __uint_as_float(hu));
}

// ---------------- weight prep ----------------
__global__ void split_arr(const float* __restrict__ src, __bf16* __restrict__ hi,
                          __bf16* __restrict__ lo, int n) {
    int i = blockIdx.x * 256 + threadIdx.x;
    if (i < n) { __bf16 h, l; split_f32(src[i], h, l); hi[i] = h; lo[i] = l; }
}

__global__ void bias_comb(const float* __restrict__ a, const float* __restrict__ b,
                          float* __restrict__ o, int n) {
    int i = blockIdx.x * 256 + threadIdx.x;
    if (i < n) o[i] = a[i] + b[i];
}

// ---------------- xp GEMM: C[M,512] = A[M,K](f32) @ W[512,K]^T + bias ----------------
#define GBM 128
#define GBN 64
#define GBK 32
#define LDA 40

__global__ __launch_bounds__(256) void gemm_xp(
    const float* __restrict__ A, const __bf16* __restrict__ Whi,
    const __bf16* __restrict__ Wlo, const float* __restrict__ bias,
    float* __restrict__ C, int K)
{
    __shared__ __bf16 sAhi[GBM*LDA], sAlo[GBM*LDA], sBhi[GBN*LDA], sBlo[GBN*LDA];
    const int tid = threadIdx.x;
    const int m0 = blockIdx.y * GBM, n0 = blockIdx.x * GBN;
    const int wave = tid >> 6, lane = tid & 63, lm = lane & 15, q = lane >> 4;

    f32x4 acc[2][4];
#pragma unroll
    for (int i = 0; i < 2; ++i)
#pragma unroll
        for (int j = 0; j < 4; ++j) acc[i][j] = (f32x4){0.f,0.f,0.f,0.f};

    for (int k0 = 0; k0 < K; k0 += GBK) {
        __syncthreads();
#pragma unroll
        for (int i = 0; i < 4; ++i) {
            int c = tid + i * 256;
            int row = c >> 3, pos = c & 7;
            float4 v = *(const float4*)(&A[(size_t)(m0+row)*K + k0 + pos*4]);
            __bf16 h0,l0,h1,l1,h2,l2,h3,l3;
            split_f32(v.x,h0,l0); split_f32(v.y,h1,l1);
            split_f32(v.z,h2,l2); split_f32(v.w,h3,l3);
            *(bf16x4*)(&sAhi[row*LDA + pos*4]) = (bf16x4){h0,h1,h2,h3};
            *(bf16x4*)(&sAlo[row*LDA + pos*4]) = (bf16x4){l0,l1,l2,l3};
        }
        {
            int row = tid >> 2, pos = (tid & 3) * 8;
            *(bf16x8*)(&sBhi[row*LDA + pos]) =
                *(const bf16x8*)(&Whi[(size_t)(n0+row)*K + k0 + pos]);
            *(bf16x8*)(&sBlo[row*LDA + pos]) =
                *(const bf16x8*)(&Wlo[(size_t)(n0+row)*K + k0 + pos]);
        }
        __syncthreads();

        bf16x8 ah[2], al[2], bh[4], bl[4];
#pragma unroll
        for (int mt = 0; mt < 2; ++mt) {
            int r = wave*32 + mt*16 + lm;
            ah[mt] = *(const bf16x8*)(&sAhi[r*LDA + q*8]);
            al[mt] = *(const bf16x8*)(&sAlo[r*LDA + q*8]);
        }
#pragma unroll
        for (int nt = 0; nt < 4; ++nt) {
            int r = nt*16 + lm;
            bh[nt] = *(const bf16x8*)(&sBhi[r*LDA + q*8]);
            bl[nt] = *(const bf16x8*)(&sBlo[r*LDA + q*8]);
        }
#pragma unroll
        for (int mt = 0; mt < 2; ++mt)
#pragma unroll
            for (int nt = 0; nt < 4; ++nt) {
                acc[mt][nt] = __builtin_amdgcn_mfma_f32_16x16x32_bf16(ah[mt], bh[nt], acc[mt][nt], 0,0,0);
                acc[mt][nt] = __builtin_amdgcn_mfma_f32_16x16x32_bf16(ah[mt], bl[nt], acc[mt][nt], 0,0,0);
                acc[mt][nt] = __builtin_amdgcn_mfma_f32_16x16x32_bf16(al[mt], bh[nt], acc[mt][nt], 0,0,0);
            }
    }
#pragma unroll
    for (int mt = 0; mt < 2; ++mt)
#pragma unroll
        for (int nt = 0; nt < 4; ++nt)
#pragma unroll
            for (int r = 0; r < 4; ++r) {
                int m = m0 + wave*32 + mt*16 + q*4 + r;
                int n = n0 + nt*16 + lm;
                C[(size_t)m*H_ + n] = acc[mt][nt][r] + bias[n];
            }
}

// ---------------- fused pipelined recurrence, data-embedded sync --------------------
// 96 blocks, 3 roles x (4 batch-groups x 8 col-blocks):
//   role0: layer-0 recurrence -> h0ring[8][B*H] u64 (lo32 = packed hi|lo bf16, hi32 = seq)
//   role1: xp1 projection     -> xp1ring[8][B*H] u64 (lo32 = fp32 bits, hi32 = seq)
//   role2: layer-1 recurrence -> h1ring[2][B*H] u64 (self-synced depth-2)
// Consumers SPIN ON THE DATA (agent-scope 8B atomic loads, seq==target): merges the
// flag RTT + data RTT into one. seq is unique per slot (seq mod depth == slot), so no
// false match; poisoned ws handled by zeroing the rings (seq=0 is only valid for t=0).
// Ring-overwrite safety: recurrence peers are self-synced (staging h_t proves peers
// finished t-1); cross-role consumers gated by slack-7 back-pressure flags, loaded at
// step start and verified just before publish (off the critical path in steady state).
#define RLDA 520     // 512 + 8 pad (bf16)
#define RDEP 8

__global__ __launch_bounds__(256, 1) void rnn_fused(
    const float* __restrict__ xp0,                       // [B,T,H] fp32 (gemm output)
    const __bf16* __restrict__ w0hi, const __bf16* __restrict__ w0lo,   // W_hh0 split
    const __bf16* __restrict__ wphi, const __bf16* __restrict__ wplo,   // W_ih1 split
    const __bf16* __restrict__ w1hi, const __bf16* __restrict__ w1lo,   // W_hh1 split
    const float* __restrict__ bias1,                     // bih1+bhh1
    u64* __restrict__ h0ring,                            // [8][B*H], zeroed
    u64* __restrict__ xp1ring,                           // [8][B*H], zeroed
    u64* __restrict__ h1ring,                            // [2][B*H], zeroed
    float* __restrict__ hlast,                           // [B,H]
    int* __restrict__ flags)                             // [2][4][16], zeroed
{
    __shared__ __bf16 sAhi[16*RLDA], sAlo[16*RLDA];
    const int tid  = threadIdx.x;
    const int role = blockIdx.x >> 5;       // 0: L0 rec, 1: proj, 2: L1 rec
    const int sub  = blockIdx.x & 31;
    const int g    = sub >> 3;              // batch group (16 rows)
    const int c    = sub & 7;               // column block (64 cols)
    const int m0g  = g * 16;
    const int n0   = c * 64;
    const int wave = tid >> 6, lane = tid & 63, lm = lane & 15, q = lane >> 4;
    const int ncol = n0 + wave*16 + lm;
    const int srow = tid >> 4, sseg = tid & 15;

    int* const flagP = flags + g*16;        // proj progress (L0 back-pressure)
    int* const flag1 = flags + 64 + g*16;   // L1 progress (proj back-pressure)

    // per-role W fragments (16 k-tiles, hi+lo = 128 VGPR)
    const __bf16* Wh = (role == 0) ? w0hi : (role == 1) ? wphi : w1hi;
    const __bf16* Wl = (role == 0) ? w0lo : (role == 1) ? wplo : w1lo;
    bf16x8 wh[16], wl[16];
#pragma unroll
    for (int kt = 0; kt < 16; ++kt) {
        wh[kt] = *(const bf16x8*)(&Wh[(size_t)ncol*H_ + kt*32 + q*8]);
        wl[kt] = *(const bf16x8*)(&Wl[(size_t)ncol*H_ + kt*32 + q*8]);
    }

    // ---- helpers ----
    // poll 16x512 h slice until every element's seq==target, unpacking to LDS planes
    auto stage_poll = [&](const u64* slot, unsigned target) {
        const u64* row = slot + (size_t)(m0g + srow) * H_;
        __bf16* dh = &sAhi[srow * RLDA];
        __bf16* dl = &sAlo[srow * RLDA];
        unsigned pend = 0xffffu;
        while (pend) {
#pragma unroll
            for (int j = 0; j < 16; ++j)
                if (pend & (1u << j)) {
                    int c0 = (sseg + j*16) * 2;
                    u64 a = __hip_atomic_load(&row[c0],   __ATOMIC_RELAXED, __HIP_MEMORY_SCOPE_AGENT);
                    u64 b = __hip_atomic_load(&row[c0+1], __ATOMIC_RELAXED, __HIP_MEMORY_SCOPE_AGENT);
                    if ((unsigned)(a >> 32) == target && (unsigned)(b >> 32) == target) {
                        unsigned pa = (unsigned)a, pb = (unsigned)b;
                        *(unsigned*)(dh + c0) = (pa >> 16) | (pb & 0xffff0000u);
                        *(unsigned*)(dl + c0) = (pa & 0xffffu) | (pb << 16);
                        pend &= ~(1u << j);
                    }
                }
        }
    };
    auto mma_tile = [&]() {
        f32x4 acc = (f32x4){0.f,0.f,0.f,0.f};
#pragma unroll
        for (int kt = 0; kt < 16; ++kt) {
            bf16x8 ah = *(const bf16x8*)(&sAhi[lm*RLDA + kt*32 + q*8]);
            bf16x8 al = *(const bf16x8*)(&sAlo[lm*RLDA + kt*32 + q*8]);
            acc = __builtin_amdgcn_mfma_f32_16x16x32_bf16(ah, wh[kt], acc, 0,0,0);
            acc = __builtin_amdgcn_mfma_f32_16x16x32_bf16(ah, wl[kt], acc, 0,0,0);
            acc = __builtin_amdgcn_mfma_f32_16x16x32_bf16(al, wh[kt], acc, 0,0,0);
        }
        return acc;
    };
    auto pack_h = [&](float hv, unsigned seq) -> u64 {
        __bf16 hh, hl; split_f32(hv, hh, hl);
        unsigned pk = ((unsigned)__builtin_bit_cast(unsigned short, hh) << 16)
                    |  (unsigned)__builtin_bit_cast(unsigned short, hl);
        return ((u64)seq << 32) | pk;
    };

    if (role == 0) {
        // ---------------- layer-0 recurrence ----------------
        for (int t = 0; t < T_; ++t) {
            // prefetch xp0 (plain loads; gemm finished pre-launch, cross-kernel coherent)
            float xr[4];
#pragma unroll
            for (int r = 0; r < 4; ++r)
                xr[r] = xp0[((size_t)(m0g + q*4 + r)*T_ + t)*H_ + ncol];
            // early-load proj back-pressure flags (verified before publish)
            const int tgt = t - (RDEP - 1);   // slot (t+1)&7 held seq t-7
            int f[8];
            if (tid == 0 && tgt > 0)
#pragma unroll
                for (int i = 0; i < 8; ++i)
                    f[i] = __hip_atomic_load(&flagP[i], __ATOMIC_RELAXED, __HIP_MEMORY_SCOPE_AGENT);

            stage_poll(h0ring + (size_t)(t & 7)*(B_*H_), (unsigned)t);
            __syncthreads();
            f32x4 acc = mma_tile();
            u64 pv[4];
#pragma unroll
            for (int r = 0; r < 4; ++r)
                pv[r] = pack_h(tanhf(xr[r] + acc[r]), (unsigned)(t+1));

            if (tid == 0 && tgt > 0) {
                bool ok = true;
#pragma unroll
                for (int i = 0; i < 8; ++i) ok &= (f[i] >= tgt);
                while (!ok) {
                    __builtin_amdgcn_s_sleep(1);
                    ok = true;
#pragma unroll
                    for (int i = 0; i < 8; ++i)
                        ok &= (__hip_atomic_load(&flagP[i], __ATOMIC_RELAXED,
                                                 __HIP_MEMORY_SCOPE_AGENT) >= tgt);
                }
            }
            __syncthreads();   // gate + LDS WAR (mma reads done before next stage)

            u64* dst = h0ring + (size_t)((t+1) & 7)*(B_*H_);
#pragma unroll
            for (int r = 0; r < 4; ++r)
                __hip_atomic_store(&dst[(size_t)(m0g + q*4 + r)*H_ + ncol], pv[r],
                                   __ATOMIC_RELAXED, __HIP_MEMORY_SCOPE_AGENT);
        }
    } else if (role == 1) {
        // ---------------- layer-1 input projection ----------------
        const float b1 = bias1[ncol];
        for (int t = 0; t < T_; ++t) {
            const int tgt = t - (RDEP - 1);   // xp1 slot t&7 held seq t-7
            int f[8];
            if (tid == 0 && tgt > 0)
#pragma unroll
                for (int i = 0; i < 8; ++i)
                    f[i] = __hip_atomic_load(&flag1[i], __ATOMIC_RELAXED, __HIP_MEMORY_SCOPE_AGENT);

            stage_poll(h0ring + (size_t)((t+1) & 7)*(B_*H_), (unsigned)(t+1)); // = out0_t
            __syncthreads();
            f32x4 acc = mma_tile();
            u64 pv[4];
#pragma unroll
            for (int r = 0; r < 4; ++r)
                pv[r] = ((u64)(unsigned)(t+1) << 32) | __float_as_uint(acc[r] + b1);

            if (tid == 0 && tgt > 0) {
                bool ok = true;
#pragma unroll
                for (int i = 0; i < 8; ++i) ok &= (f[i] >= tgt);
                while (!ok) {
                    __builtin_amdgcn_s_sleep(1);
                    ok = true;
#pragma unroll
                    for (int i = 0; i < 8; ++i)
                        ok &= (__hip_atomic_load(&flag1[i], __ATOMIC_RELAXED,
                                                 __HIP_MEMORY_SCOPE_AGENT) >= tgt);
                }
            }
            __syncthreads();

            u64* dst = xp1ring + (size_t)(t & 7)*(B_*H_);
#pragma unroll
            for (int r = 0; r < 4; ++r)
                __hip_atomic_store(&dst[(size_t)(m0g + q*4 + r)*H_ + ncol], pv[r],
                                   __ATOMIC_RELAXED, __HIP_MEMORY_SCOPE_AGENT);
            if (tid == 0)
                __hip_atomic_store(&flagP[c], t+1, __ATOMIC_RELEASE, __HIP_MEMORY_SCOPE_AGENT);
        }
    } else {
        // ---------------- layer-1 recurrence ----------------
        for (int t = 0; t < T_; ++t) {
            // h1_t is own-group (published one lag ago) -> stage first, nearly instant
            stage_poll(h1ring + (size_t)(t & 1)*(B_*H_), (unsigned)t);
            // xp1_t is the laggard (arrives ~1 L0-period later) -> poll it second
            u64 xv[4];
            {
                const u64* xs = xp1ring + (size_t)(t & 7)*(B_*H_);
                unsigned pend = 0xfu;
                while (pend) {
#pragma unroll
                    for (int r = 0; r < 4; ++r)
                        if (pend & (1u << r)) {
                            u64 v = __hip_atomic_load(&xs[(size_t)(m0g + q*4 + r)*H_ + ncol],
                                                      __ATOMIC_RELAXED, __HIP_MEMORY_SCOPE_AGENT);
                            if ((unsigned)(v >> 32) == (unsigned)(t+1)) { xv[r] = v; pend &= ~(1u << r); }
                        }
                }
            }
            __syncthreads();
            f32x4 acc = mma_tile();
            float hv[4]; u64 pv[4];
#pragma unroll
            for (int r = 0; r < 4; ++r) {
                hv[r] = tanhf(__uint_as_float((unsigned)xv[r]) + acc[r]);
                pv[r] = pack_h(hv[r], (unsigned)(t+1));
            }
            __syncthreads();   // LDS WAR before next stage

            u64* dst = h1ring + (size_t)((t+1) & 1)*(B_*H_);
#pragma unroll
            for (int r = 0; r < 4; ++r) {
                int m = m0g + q*4 + r;
                __hip_atomic_store(&dst[(size_t)m*H_ + ncol], pv[r],
                                   __ATOMIC_RELAXED, __HIP_MEMORY_SCOPE_AGENT);
                if (t == T_-1) hlast[(size_t)m*H_ + ncol] = hv[r];
            }
            if (tid == 0)
                __hip_atomic_store(&flag1[c], t+1, __ATOMIC_RELEASE, __HIP_MEMORY_SCOPE_AGENT);
        }
    }
}

// ---------------- output projection ----------------
__global__ __launch_bounds__(256) void out_proj(
    const float* __restrict__ hlast, const float* __restrict__ Wout,
    const float* __restrict__ bout, float* __restrict__ out)
{
    __shared__ float sh[H_];
    int b = blockIdx.x;
    for (int i = threadIdx.x; i < H_; i += 256) sh[i] = hlast[(size_t)b*H_ + i];
    __syncthreads();
    int o = threadIdx.x;
    const float* wr = &Wout[(size_t)o*H_];
    float acc = 0.f;
#pragma unroll 4
    for (int k = 0; k < H_; k += 4) {
        float4 wv = *(const float4*)(&wr[k]);
        acc += wv.x*sh[k] + wv.y*sh[k+1] + wv.z*sh[k+2] + wv.w*sh[k+3];
    }
    out[(size_t)b*OUT_ + o] = bout[o] + acc;
}

extern "C" void kernel_launch(void* const* d_in, const int* in_sizes, int n_in,
                              void* d_out, int out_size, void* d_ws, size_t ws_size,
                              hipStream_t stream)
{
    const float* x    = (const float*)d_in[0];
    const float* Wih0 = (const float*)d_in[1];
    const float* Whh0 = (const float*)d_in[2];
    const float* bih0 = (const float*)d_in[3];
    const float* bhh0 = (const float*)d_in[4];
    const float* Wih1 = (const float*)d_in[5];
    const float* Whh1 = (const float*)d_in[6];
    const float* bih1 = (const float*)d_in[7];
    const float* bhh1 = (const float*)d_in[8];
    const float* Wout = (const float*)d_in[9];
    const float* bout = (const float*)d_in[10];

    char* w = (char*)d_ws;
    size_t off = 0;
    auto alloc = [&](size_t bytes) -> void* {
        void* p = w + off; off = (off + bytes + 255) & ~(size_t)255; return p;
    };
    float*  xp     = (float*) alloc((size_t)M_*H_*4);      // 64 MB xp0 (read-only in fused)
    __bf16* wih0hi = (__bf16*)alloc((size_t)H_*IN_*2);
    __bf16* wih0lo = (__bf16*)alloc((size_t)H_*IN_*2);
    __bf16* whh0hi = (__bf16*)alloc((size_t)H_*H_*2);
    __bf16* whh0lo = (__bf16*)alloc((size_t)H_*H_*2);
    __bf16* wih1hi = (__bf16*)alloc((size_t)H_*H_*2);
    __bf16* wih1lo = (__bf16*)alloc((size_t)H_*H_*2);
    __bf16* whh1hi = (__bf16*)alloc((size_t)H_*H_*2);
    __bf16* whh1lo = (__bf16*)alloc((size_t)H_*H_*2);
    float*  bias0  = (float*) alloc(H_*4);
    float*  bias1  = (float*) alloc(H_*4);
    size_t zstart = off;                                   // zero-init region start
    u64*    h0ring = (u64*)   alloc((size_t)RDEP*B_*H_*8); // 2 MB
    u64*    xp1ring= (u64*)   alloc((size_t)RDEP*B_*H_*8); // 2 MB
    u64*    h1ring = (u64*)   alloc((size_t)2*B_*H_*8);    // 512 KB
    int*    flags  = (int*)   alloc(512);                  // [2][4][16]
    size_t zlen = off - zstart;
    float*  hlast  = (float*) alloc((size_t)B_*H_*4);

    // zero rings + flags (ws is poisoned before every launch; seq fields must start 0)
    hipMemsetAsync(w + zstart, 0, zlen, stream);

    // weight split + bias combine
    split_arr<<<(H_*IN_+255)/256, 256, 0, stream>>>(Wih0, wih0hi, wih0lo, H_*IN_);
    split_arr<<<(H_*H_ +255)/256, 256, 0, stream>>>(Whh0, whh0hi, whh0lo, H_*H_);
    split_arr<<<(H_*H_ +255)/256, 256, 0, stream>>>(Wih1, wih1hi, wih1lo, H_*H_);
    split_arr<<<(H_*H_ +255)/256, 256, 0, stream>>>(Whh1, whh1hi, whh1lo, H_*H_);
    bias_comb<<<2, 256, 0, stream>>>(bih0, bhh0, bias0, H_);
    bias_comb<<<2, 256, 0, stream>>>(bih1, bhh1, bias1, H_);

    // layer-0 input projection (one big GEMM, K=256)
    dim3 ggrid(H_/GBN, M_/GBM);  // (8, 256)
    gemm_xp<<<ggrid, 256, 0, stream>>>(x, wih0hi, wih0lo, bias0, xp, IN_);

    // fused pipelined recurrences (layer0 -> proj -> layer1), data-embedded sync
    rnn_fused<<<96, 256, 0, stream>>>(xp, whh0hi, whh0lo, wih1hi, wih1lo,
                                      whh1hi, whh1lo, bias1,
                                      h0ring, xp1ring, h1ring, hlast, flags);

    // output projection
    out_proj<<<B_, 256, 0, stream>>>(hlast, Wout, bout, (float*)d_out);
}

// Round 5
// 4560.891 us; speedup vs baseline: 1.0763x; 1.0763x over previous
//
#include <hip/hip_runtime.h>
#include <cmath>

#define B_   64
#define T_   512
#define IN_  256
#define H_   512
#define OUT_ 256
#define M_   (B_*T_)   // 32768 rows for the input-projection GEMM

typedef __bf16 bf16x4 __attribute__((ext_vector_type(4)));
typedef __bf16 bf16x8 __attribute__((ext_vector_type(8)));
typedef float  f32x4  __attribute__((ext_vector_type(4)));
typedef unsigned long long u64;

// Split fp32 into bf16 hi (truncated, exact) + bf16 lo (RN of remainder).
static __device__ __forceinline__ void split_f32(float x, __bf16 &hi, __bf16 &lo) {
    unsigned u  = __float_as_uint(x);
    unsigned hu = u & 0xffff0000u;
    hi = __builtin_bit_cast(__bf16, (unsigned short)(hu >> 16));
    lo = (__bf16)(x - __uint_as_float(hu));
}

// s_sleep requires a literal operand -> constant-dispatch the escalating pace.
static __device__ __forceinline__ void pace(int sl) {
    switch (sl) {
        case 0: break;
        case 1: __builtin_amdgcn_s_sleep(1); break;
        case 2: __builtin_amdgcn_s_sleep(2); break;
        case 4: __builtin_amdgcn_s_sleep(4); break;
        default: __builtin_amdgcn_s_sleep(8); break;
    }
}

// ---------------- weight prep ----------------
__global__ void split_arr(const float* __restrict__ src, __bf16* __restrict__ hi,
                          __bf16* __restrict__ lo, int n) {
    int i = blockIdx.x * 256 + threadIdx.x;
    if (i < n) { __bf16 h, l; split_f32(src[i], h, l); hi[i] = h; lo[i] = l; }
}

__global__ void bias_comb(const float* __restrict__ a, const float* __restrict__ b,
                          float* __restrict__ o, int n) {
    int i = blockIdx.x * 256 + threadIdx.x;
    if (i < n) o[i] = a[i] + b[i];
}

// ---------------- xp GEMM: C[M,512] = A[M,K](f32) @ W[512,K]^T + bias ----------------
#define GBM 128
#define GBN 64
#define GBK 32
#define LDA 40

__global__ __launch_bounds__(256) void gemm_xp(
    const float* __restrict__ A, const __bf16* __restrict__ Whi,
    const __bf16* __restrict__ Wlo, const float* __restrict__ bias,
    float* __restrict__ C, int K)
{
    __shared__ __bf16 sAhi[GBM*LDA], sAlo[GBM*LDA], sBhi[GBN*LDA], sBlo[GBN*LDA];
    const int tid = threadIdx.x;
    const int m0 = blockIdx.y * GBM, n0 = blockIdx.x * GBN;
    const int wave = tid >> 6, lane = tid & 63, lm = lane & 15, q = lane >> 4;

    f32x4 acc[2][4];
#pragma unroll
    for (int i = 0; i < 2; ++i)
#pragma unroll
        for (int j = 0; j < 4; ++j) acc[i][j] = (f32x4){0.f,0.f,0.f,0.f};

    for (int k0 = 0; k0 < K; k0 += GBK) {
        __syncthreads();
#pragma unroll
        for (int i = 0; i < 4; ++i) {
            int c = tid + i * 256;
            int row = c >> 3, pos = c & 7;
            float4 v = *(const float4*)(&A[(size_t)(m0+row)*K + k0 + pos*4]);
            __bf16 h0,l0,h1,l1,h2,l2,h3,l3;
            split_f32(v.x,h0,l0); split_f32(v.y,h1,l1);
            split_f32(v.z,h2,l2); split_f32(v.w,h3,l3);
            *(bf16x4*)(&sAhi[row*LDA + pos*4]) = (bf16x4){h0,h1,h2,h3};
            *(bf16x4*)(&sAlo[row*LDA + pos*4]) = (bf16x4){l0,l1,l2,l3};
        }
        {
            int row = tid >> 2, pos = (tid & 3) * 8;
            *(bf16x8*)(&sBhi[row*LDA + pos]) =
                *(const bf16x8*)(&Whi[(size_t)(n0+row)*K + k0 + pos]);
            *(bf16x8*)(&sBlo[row*LDA + pos]) =
                *(const bf16x8*)(&Wlo[(size_t)(n0+row)*K + k0 + pos]);
        }
        __syncthreads();

        bf16x8 ah[2], al[2], bh[4], bl[4];
#pragma unroll
        for (int mt = 0; mt < 2; ++mt) {
            int r = wave*32 + mt*16 + lm;
            ah[mt] = *(const bf16x8*)(&sAhi[r*LDA + q*8]);
            al[mt] = *(const bf16x8*)(&sAlo[r*LDA + q*8]);
        }
#pragma unroll
        for (int nt = 0; nt < 4; ++nt) {
            int r = nt*16 + lm;
            bh[nt] = *(const bf16x8*)(&sBhi[r*LDA + q*8]);
            bl[nt] = *(const bf16x8*)(&sBlo[r*LDA + q*8]);
        }
#pragma unroll
        for (int mt = 0; mt < 2; ++mt)
#pragma unroll
            for (int nt = 0; nt < 4; ++nt) {
                acc[mt][nt] = __builtin_amdgcn_mfma_f32_16x16x32_bf16(ah[mt], bh[nt], acc[mt][nt], 0,0,0);
                acc[mt][nt] = __builtin_amdgcn_mfma_f32_16x16x32_bf16(ah[mt], bl[nt], acc[mt][nt], 0,0,0);
                acc[mt][nt] = __builtin_amdgcn_mfma_f32_16x16x32_bf16(al[mt], bh[nt], acc[mt][nt], 0,0,0);
            }
    }
#pragma unroll
    for (int mt = 0; mt < 2; ++mt)
#pragma unroll
        for (int nt = 0; nt < 4; ++nt)
#pragma unroll
            for (int r = 0; r < 4; ++r) {
                int m = m0 + wave*32 + mt*16 + q*4 + r;
                int n = n0 + nt*16 + lm;
                C[(size_t)m*H_ + n] = acc[mt][nt][r] + bias[n];
            }
}

// ---------------- fused pipelined recurrence, data-embedded sync v2 -----------------
// 96 blocks, 3 roles x (4 batch-groups x 8 col-blocks). Producers publish u64 words
// (lo32 = payload, hi32 = seq) fire-and-forget; consumers poll the DATA with paced,
// escalating retries (s_sleep 1->8). No drains anywhere. Back-pressure flags are
// consumption signals stored right after the staging barrier (lazy-checked, slack 7).
#define RLDA 520     // 512 + 8 pad (bf16)
#define RDEP 8

__global__ __launch_bounds__(256, 1) void rnn_fused(
    const float* __restrict__ xp0,                       // [B,T,H] fp32 (gemm output)
    const __bf16* __restrict__ w0hi, const __bf16* __restrict__ w0lo,   // W_hh0 split
    const __bf16* __restrict__ wphi, const __bf16* __restrict__ wplo,   // W_ih1 split
    const __bf16* __restrict__ w1hi, const __bf16* __restrict__ w1lo,   // W_hh1 split
    const float* __restrict__ bias1,                     // bih1+bhh1
    u64* __restrict__ h0ring,                            // [8][B*H], zeroed
    u64* __restrict__ xp1ring,                           // [8][B*H], zeroed
    u64* __restrict__ h1ring,                            // [2][B*H], zeroed
    float* __restrict__ hlast,                           // [B,H]
    int* __restrict__ flags)                             // [2][4][16], zeroed
{
    __shared__ __bf16 sAhi[16*RLDA], sAlo[16*RLDA];
    const int tid  = threadIdx.x;
    const int role = blockIdx.x >> 5;       // 0: L0 rec, 1: proj, 2: L1 rec
    const int sub  = blockIdx.x & 31;
    const int g    = sub >> 3;              // batch group (16 rows)
    const int c    = sub & 7;               // column block (64 cols)
    const int m0g  = g * 16;
    const int n0   = c * 64;
    const int wave = tid >> 6, lane = tid & 63, lm = lane & 15, q = lane >> 4;
    const int ncol = n0 + wave*16 + lm;
    const int srow = tid >> 4, sseg = tid & 15;

    int* const flagP = flags + g*16;        // proj staged h0 seq v  (L0 back-pressure)
    int* const flag1 = flags + 64 + g*16;   // L1 consumed xp1_t -> t+1 (proj back-pressure)

    // per-role W fragments (16 k-tiles, hi+lo = 128 VGPR)
    const __bf16* Wh = (role == 0) ? w0hi : (role == 1) ? wphi : w1hi;
    const __bf16* Wl = (role == 0) ? w0lo : (role == 1) ? wplo : w1lo;
    bf16x8 wh[16], wl[16];
#pragma unroll
    for (int kt = 0; kt < 16; ++kt) {
        wh[kt] = *(const bf16x8*)(&Wh[(size_t)ncol*H_ + kt*32 + q*8]);
        wl[kt] = *(const bf16x8*)(&Wl[(size_t)ncol*H_ + kt*32 + q*8]);
    }

    // ---- helpers ----
    // poll 16x512 slice until every element's seq==target; unpack to LDS planes.
    // Paced: first pass issues all loads; retries sleep with escalation.
    auto stage_poll = [&](const u64* slot, unsigned target) {
        const u64* row = slot + (size_t)(m0g + srow) * H_;
        __bf16* dh = &sAhi[srow * RLDA];
        __bf16* dl = &sAlo[srow * RLDA];
        unsigned pend = 0xffffu;
        int sl = 0;
        while (pend) {
            pace(sl);
            sl = sl ? (sl < 8 ? sl*2 : 8) : 1;
#pragma unroll
            for (int j = 0; j < 16; ++j)
                if (pend & (1u << j)) {
                    int c0 = (sseg + j*16) * 2;
                    u64 a = __hip_atomic_load(&row[c0],   __ATOMIC_RELAXED, __HIP_MEMORY_SCOPE_AGENT);
                    u64 b = __hip_atomic_load(&row[c0+1], __ATOMIC_RELAXED, __HIP_MEMORY_SCOPE_AGENT);
                    if ((unsigned)(a >> 32) == target && (unsigned)(b >> 32) == target) {
                        unsigned pa = (unsigned)a, pb = (unsigned)b;
                        *(unsigned*)(dh + c0) = (pa >> 16) | (pb & 0xffff0000u);
                        *(unsigned*)(dl + c0) = (pa & 0xffffu) | (pb << 16);
                        pend &= ~(1u << j);
                    }
                }
        }
    };
    auto mma_tile = [&]() {
        f32x4 acc = (f32x4){0.f,0.f,0.f,0.f};
#pragma unroll
        for (int kt = 0; kt < 16; ++kt) {
            bf16x8 ah = *(const bf16x8*)(&sAhi[lm*RLDA + kt*32 + q*8]);
            bf16x8 al = *(const bf16x8*)(&sAlo[lm*RLDA + kt*32 + q*8]);
            acc = __builtin_amdgcn_mfma_f32_16x16x32_bf16(ah, wh[kt], acc, 0,0,0);
            acc = __builtin_amdgcn_mfma_f32_16x16x32_bf16(ah, wl[kt], acc, 0,0,0);
            acc = __builtin_amdgcn_mfma_f32_16x16x32_bf16(al, wh[kt], acc, 0,0,0);
        }
        return acc;
    };
    auto pack_h = [&](float hv, unsigned seq) -> u64 {
        __bf16 hh, hl; split_f32(hv, hh, hl);
        unsigned pk = ((unsigned)__builtin_bit_cast(unsigned short, hh) << 16)
                    |  (unsigned)__builtin_bit_cast(unsigned short, hl);
        return ((u64)seq << 32) | pk;
    };

    if (role == 0) {
        // ---------------- layer-0 recurrence ----------------
        for (int t = 0; t < T_; ++t) {
            float xr[4];
#pragma unroll
            for (int r = 0; r < 4; ++r)
                xr[r] = xp0[((size_t)(m0g + q*4 + r)*T_ + t)*H_ + ncol];
            const int tgt = t - (RDEP - 1);   // slot (t+1)&7 held seq t-7
            int f[8];
            if (tid == 0 && tgt > 0)
#pragma unroll
                for (int i = 0; i < 8; ++i)
                    f[i] = __hip_atomic_load(&flagP[i], __ATOMIC_RELAXED, __HIP_MEMORY_SCOPE_AGENT);

            stage_poll(h0ring + (size_t)(t & 7)*(B_*H_), (unsigned)t);
            __syncthreads();
            f32x4 acc = mma_tile();
            u64 pv[4];
#pragma unroll
            for (int r = 0; r < 4; ++r)
                pv[r] = pack_h(tanhf(xr[r] + acc[r]), (unsigned)(t+1));

            if (tid == 0 && tgt > 0) {
                bool ok = true;
#pragma unroll
                for (int i = 0; i < 8; ++i) ok &= (f[i] >= tgt);
                int sl = 1;
                while (!ok) {
                    pace(sl); if (sl < 8) sl *= 2;
                    ok = true;
#pragma unroll
                    for (int i = 0; i < 8; ++i)
                        ok &= (__hip_atomic_load(&flagP[i], __ATOMIC_RELAXED,
                                                 __HIP_MEMORY_SCOPE_AGENT) >= tgt);
                }
            }
            __syncthreads();   // gate + LDS WAR (mma reads done before next stage)

            u64* dst = h0ring + (size_t)((t+1) & 7)*(B_*H_);
#pragma unroll
            for (int r = 0; r < 4; ++r)
                __hip_atomic_store(&dst[(size_t)(m0g + q*4 + r)*H_ + ncol], pv[r],
                                   __ATOMIC_RELAXED, __HIP_MEMORY_SCOPE_AGENT);
        }
    } else if (role == 1) {
        // ---------------- layer-1 input projection ----------------
        const float b1 = bias1[ncol];
        for (int t = 0; t < T_; ++t) {
            const int tgt = t - (RDEP - 1);   // xp1 slot t&7 held seq t-7
            int f[8];
            if (tid == 0 && tgt > 0)
#pragma unroll
                for (int i = 0; i < 8; ++i)
                    f[i] = __hip_atomic_load(&flag1[i], __ATOMIC_RELAXED, __HIP_MEMORY_SCOPE_AGENT);

            stage_poll(h0ring + (size_t)((t+1) & 7)*(B_*H_), (unsigned)(t+1)); // = out0_t
            __syncthreads();
            if (tid == 0)   // consumption signal: done reading h0 slot (t+1)&7
                __hip_atomic_store(&flagP[c], t+1, __ATOMIC_RELAXED, __HIP_MEMORY_SCOPE_AGENT);
            f32x4 acc = mma_tile();
            u64 pv[4];
#pragma unroll
            for (int r = 0; r < 4; ++r)
                pv[r] = ((u64)(unsigned)(t+1) << 32) | __float_as_uint(acc[r] + b1);

            if (tid == 0 && tgt > 0) {
                bool ok = true;
#pragma unroll
                for (int i = 0; i < 8; ++i) ok &= (f[i] >= tgt);
                int sl = 1;
                while (!ok) {
                    pace(sl); if (sl < 8) sl *= 2;
                    ok = true;
#pragma unroll
                    for (int i = 0; i < 8; ++i)
                        ok &= (__hip_atomic_load(&flag1[i], __ATOMIC_RELAXED,
                                                 __HIP_MEMORY_SCOPE_AGENT) >= tgt);
                }
            }
            __syncthreads();

            u64* dst = xp1ring + (size_t)(t & 7)*(B_*H_);
#pragma unroll
            for (int r = 0; r < 4; ++r)
                __hip_atomic_store(&dst[(size_t)(m0g + q*4 + r)*H_ + ncol], pv[r],
                                   __ATOMIC_RELAXED, __HIP_MEMORY_SCOPE_AGENT);
        }
    } else {
        // ---------------- layer-1 recurrence ----------------
        for (int t = 0; t < T_; ++t) {
            // combined paced poll: h1_t slice (16 pairs -> LDS) AND xp1_t (4 words -> regs)
            u64 xv[4];
            {
                const u64* hrow = h1ring + (size_t)(t & 1)*(B_*H_) + (size_t)(m0g + srow)*H_;
                const u64* xs   = xp1ring + (size_t)(t & 7)*(B_*H_);
                __bf16* dh = &sAhi[srow*RLDA];
                __bf16* dl = &sAlo[srow*RLDA];
                unsigned pend = 0xffffu, pendx = 0xfu;
                int sl = 0;
                while (pend | pendx) {
                    pace(sl);
                    sl = sl ? (sl < 8 ? sl*2 : 8) : 1;
#pragma unroll
                    for (int j = 0; j < 16; ++j)
                        if (pend & (1u << j)) {
                            int c0 = (sseg + j*16) * 2;
                            u64 a = __hip_atomic_load(&hrow[c0],   __ATOMIC_RELAXED, __HIP_MEMORY_SCOPE_AGENT);
                            u64 b = __hip_atomic_load(&hrow[c0+1], __ATOMIC_RELAXED, __HIP_MEMORY_SCOPE_AGENT);
                            if ((unsigned)(a >> 32) == (unsigned)t && (unsigned)(b >> 32) == (unsigned)t) {
                                unsigned pa = (unsigned)a, pb = (unsigned)b;
                                *(unsigned*)(dh + c0) = (pa >> 16) | (pb & 0xffff0000u);
                                *(unsigned*)(dl + c0) = (pa & 0xffffu) | (pb << 16);
                                pend &= ~(1u << j);
                            }
                        }
#pragma unroll
                    for (int r = 0; r < 4; ++r)
                        if (pendx & (1u << r)) {
                            u64 v = __hip_atomic_load(&xs[(size_t)(m0g + q*4 + r)*H_ + ncol],
                                                      __ATOMIC_RELAXED, __HIP_MEMORY_SCOPE_AGENT);
                            if ((unsigned)(v >> 32) == (unsigned)(t+1)) { xv[r] = v; pendx &= ~(1u << r); }
                        }
                }
            }
            __syncthreads();
            if (tid == 0)   // consumption signal: xp1_t read by whole block
                __hip_atomic_store(&flag1[c], t+1, __ATOMIC_RELAXED, __HIP_MEMORY_SCOPE_AGENT);
            f32x4 acc = mma_tile();
            float hv[4]; u64 pv[4];
#pragma unroll
            for (int r = 0; r < 4; ++r) {
                hv[r] = tanhf(__uint_as_float((unsigned)xv[r]) + acc[r]);
                pv[r] = pack_h(hv[r], (unsigned)(t+1));
            }
            __syncthreads();   // LDS WAR before next stage

            u64* dst = h1ring + (size_t)((t+1) & 1)*(B_*H_);
#pragma unroll
            for (int r = 0; r < 4; ++r) {
                int m = m0g + q*4 + r;
                __hip_atomic_store(&dst[(size_t)m*H_ + ncol], pv[r],
                                   __ATOMIC_RELAXED, __HIP_MEMORY_SCOPE_AGENT);
                if (t == T_-1) hlast[(size_t)m*H_ + ncol] = hv[r];
            }
        }
    }
}

// ---------------- output projection ----------------
__global__ __launch_bounds__(256) void out_proj(
    const float* __restrict__ hlast, const float* __restrict__ Wout,
    const float* __restrict__ bout, float* __restrict__ out)
{
    __shared__ float sh[H_];
    int b = blockIdx.x;
    for (int i = threadIdx.x; i < H_; i += 256) sh[i] = hlast[(size_t)b*H_ + i];
    __syncthreads();
    int o = threadIdx.x;
    const float* wr = &Wout[(size_t)o*H_];
    float acc = 0.f;
#pragma unroll 4
    for (int k = 0; k < H_; k += 4) {
        float4 wv = *(const float4*)(&wr[k]);
        acc += wv.x*sh[k] + wv.y*sh[k+1] + wv.z*sh[k+2] + wv.w*sh[k+3];
    }
    out[(size_t)b*OUT_ + o] = bout[o] + acc;
}

extern "C" void kernel_launch(void* const* d_in, const int* in_sizes, int n_in,
                              void* d_out, int out_size, void* d_ws, size_t ws_size,
                              hipStream_t stream)
{
    const float* x    = (const float*)d_in[0];
    const float* Wih0 = (const float*)d_in[1];
    const float* Whh0 = (const float*)d_in[2];
    const float* bih0 = (const float*)d_in[3];
    const float* bhh0 = (const float*)d_in[4];
    const float* Wih1 = (const float*)d_in[5];
    const float* Whh1 = (const float*)d_in[6];
    const float* bih1 = (const float*)d_in[7];
    const float* bhh1 = (const float*)d_in[8];
    const float* Wout = (const float*)d_in[9];
    const float* bout = (const float*)d_in[10];

    char* w = (char*)d_ws;
    size_t off = 0;
    auto alloc = [&](size_t bytes) -> void* {
        void* p = w + off; off = (off + bytes + 255) & ~(size_t)255; return p;
    };
    float*  xp     = (float*) alloc((size_t)M_*H_*4);      // 64 MB xp0 (read-only in fused)
    __bf16* wih0hi = (__bf16*)alloc((size_t)H_*IN_*2);
    __bf16* wih0lo = (__bf16*)alloc((size_t)H_*IN_*2);
    __bf16* whh0hi = (__bf16*)alloc((size_t)H_*H_*2);
    __bf16* whh0lo = (__bf16*)alloc((size_t)H_*H_*2);
    __bf16* wih1hi = (__bf16*)alloc((size_t)H_*H_*2);
    __bf16* wih1lo = (__bf16*)alloc((size_t)H_*H_*2);
    __bf16* whh1hi = (__bf16*)alloc((size_t)H_*H_*2);
    __bf16* whh1lo = (__bf16*)alloc((size_t)H_*H_*2);
    float*  bias0  = (float*) alloc(H_*4);
    float*  bias1  = (float*) alloc(H_*4);
    size_t zstart = off;                                   // zero-init region start
    u64*    h0ring = (u64*)   alloc((size_t)RDEP*B_*H_*8); // 2 MB
    u64*    xp1ring= (u64*)   alloc((size_t)RDEP*B_*H_*8); // 2 MB
    u64*    h1ring = (u64*)   alloc((size_t)2*B_*H_*8);    // 512 KB
    int*    flags  = (int*)   alloc(512);                  // [2][4][16]
    size_t zlen = off - zstart;
    float*  hlast  = (float*) alloc((size_t)B_*H_*4);

    // zero rings + flags (ws is poisoned before every launch; seq fields must start 0)
    hipMemsetAsync(w + zstart, 0, zlen, stream);

    // weight split + bias combine
    split_arr<<<(H_*IN_+255)/256, 256, 0, stream>>>(Wih0, wih0hi, wih0lo, H_*IN_);
    split_arr<<<(H_*H_ +255)/256, 256, 0, stream>>>(Whh0, whh0hi, whh0lo, H_*H_);
    split_arr<<<(H_*H_ +255)/256, 256, 0, stream>>>(Wih1, wih1hi, wih1lo, H_*H_);
    split_arr<<<(H_*H_ +255)/256, 256, 0, stream>>>(Whh1, whh1hi, whh1lo, H_*H_);
    bias_comb<<<2, 256, 0, stream>>>(bih0, bhh0, bias0, H_);
    bias_comb<<<2, 256, 0, stream>>>(bih1, bhh1, bias1, H_);

    // layer-0 input projection (one big GEMM, K=256)
    dim3 ggrid(H_/GBN, M_/GBM);  // (8, 256)
    gemm_xp<<<ggrid, 256, 0, stream>>>(x, wih0hi, wih0lo, bias0, xp, IN_);

    // fused pipelined recurrences (layer0 -> proj -> layer1), paced data-embedded sync
    rnn_fused<<<96, 256, 0, stream>>>(xp, whh0hi, whh0lo, wih1hi, wih1lo,
                                      whh1hi, whh1lo, bias1,
                                      h0ring, xp1ring, h1ring, hlast, flags);

    // output projection
    out_proj<<<B_, 256, 0, stream>>>(hlast, Wout, bout, (float*)d_out);
}

// Round 6
// 2775.613 us; speedup vs baseline: 1.7685x; 1.6432x over previous
//
#include <hip/hip_runtime.h>
#include <cmath>

#define B_   64
#define T_   512
#define IN_  256
#define H_   512
#define OUT_ 256
#define M_   (B_*T_)   // 32768 rows for the input-projection GEMM

typedef __bf16 bf16x4 __attribute__((ext_vector_type(4)));
typedef __bf16 bf16x8 __attribute__((ext_vector_type(8)));
typedef float  f32x4  __attribute__((ext_vector_type(4)));
typedef unsigned long long u64;

// Split fp32 into bf16 hi (truncated, exact) + bf16 lo (RN of remainder).
static __device__ __forceinline__ void split_f32(float x, __bf16 &hi, __bf16 &lo) {
    unsigned u  = __float_as_uint(x);
    unsigned hu = u & 0xffff0000u;
    hi = __builtin_bit_cast(__bf16, (unsigned short)(hu >> 16));
    lo = (__bf16)(x - __uint_as_float(hu));
}

// ---------------- weight prep ----------------
__global__ void split_arr(const float* __restrict__ src, __bf16* __restrict__ hi,
                          __bf16* __restrict__ lo, int n) {
    int i = blockIdx.x * 256 + threadIdx.x;
    if (i < n) { __bf16 h, l; split_f32(src[i], h, l); hi[i] = h; lo[i] = l; }
}

__global__ void bias_comb(const float* __restrict__ a, const float* __restrict__ b,
                          float* __restrict__ o, int n) {
    int i = blockIdx.x * 256 + threadIdx.x;
    if (i < n) o[i] = a[i] + b[i];
}

// ---------------- xp GEMM: C[M,512] = A[M,K](f32) @ W[512,K]^T + bias ----------------
#define GBM 128
#define GBN 64
#define GBK 32
#define LDA 40

__global__ __launch_bounds__(256) void gemm_xp(
    const float* __restrict__ A, const __bf16* __restrict__ Whi,
    const __bf16* __restrict__ Wlo, const float* __restrict__ bias,
    float* __restrict__ C, int K)
{
    __shared__ __bf16 sAhi[GBM*LDA], sAlo[GBM*LDA], sBhi[GBN*LDA], sBlo[GBN*LDA];
    const int tid = threadIdx.x;
    const int m0 = blockIdx.y * GBM, n0 = blockIdx.x * GBN;
    const int wave = tid >> 6, lane = tid & 63, lm = lane & 15, q = lane >> 4;

    f32x4 acc[2][4];
#pragma unroll
    for (int i = 0; i < 2; ++i)
#pragma unroll
        for (int j = 0; j < 4; ++j) acc[i][j] = (f32x4){0.f,0.f,0.f,0.f};

    for (int k0 = 0; k0 < K; k0 += GBK) {
        __syncthreads();
#pragma unroll
        for (int i = 0; i < 4; ++i) {
            int c = tid + i * 256;
            int row = c >> 3, pos = c & 7;
            float4 v = *(const float4*)(&A[(size_t)(m0+row)*K + k0 + pos*4]);
            __bf16 h0,l0,h1,l1,h2,l2,h3,l3;
            split_f32(v.x,h0,l0); split_f32(v.y,h1,l1);
            split_f32(v.z,h2,l2); split_f32(v.w,h3,l3);
            *(bf16x4*)(&sAhi[row*LDA + pos*4]) = (bf16x4){h0,h1,h2,h3};
            *(bf16x4*)(&sAlo[row*LDA + pos*4]) = (bf16x4){l0,l1,l2,l3};
        }
        {
            int row = tid >> 2, pos = (tid & 3) * 8;
            *(bf16x8*)(&sBhi[row*LDA + pos]) =
                *(const bf16x8*)(&Whi[(size_t)(n0+row)*K + k0 + pos]);
            *(bf16x8*)(&sBlo[row*LDA + pos]) =
                *(const bf16x8*)(&Wlo[(size_t)(n0+row)*K + k0 + pos]);
        }
        __syncthreads();

        bf16x8 ah[2], al[2], bh[4], bl[4];
#pragma unroll
        for (int mt = 0; mt < 2; ++mt) {
            int r = wave*32 + mt*16 + lm;
            ah[mt] = *(const bf16x8*)(&sAhi[r*LDA + q*8]);
            al[mt] = *(const bf16x8*)(&sAlo[r*LDA + q*8]);
        }
#pragma unroll
        for (int nt = 0; nt < 4; ++nt) {
            int r = nt*16 + lm;
            bh[nt] = *(const bf16x8*)(&sBhi[r*LDA + q*8]);
            bl[nt] = *(const bf16x8*)(&sBlo[r*LDA + q*8]);
        }
#pragma unroll
        for (int mt = 0; mt < 2; ++mt)
#pragma unroll
            for (int nt = 0; nt < 4; ++nt) {
                acc[mt][nt] = __builtin_amdgcn_mfma_f32_16x16x32_bf16(ah[mt], bh[nt], acc[mt][nt], 0,0,0);
                acc[mt][nt] = __builtin_amdgcn_mfma_f32_16x16x32_bf16(ah[mt], bl[nt], acc[mt][nt], 0,0,0);
                acc[mt][nt] = __builtin_amdgcn_mfma_f32_16x16x32_bf16(al[mt], bh[nt], acc[mt][nt], 0,0,0);
            }
    }
#pragma unroll
    for (int mt = 0; mt < 2; ++mt)
#pragma unroll
        for (int nt = 0; nt < 4; ++nt)
#pragma unroll
            for (int r = 0; r < 4; ++r) {
                int m = m0 + wave*32 + mt*16 + q*4 + r;
                int n = n0 + nt*16 + lm;
                C[(size_t)m*H_ + n] = acc[mt][nt][r] + bias[n];
            }
}

// ---------------- fused 2-role recurrence (proj folded into L0) ---------------------
// 64 blocks = 2 roles x (4 batch-groups x 8 col-blocks).
//  role0: L0 recurrence + inline xp1 projection. Per step t: stage h0_t (flag-synced
//         u32 ring, depth 8), mma W_hh0 -> publish h0(t+1)+flag0; then mma W_ih1 on
//         the SAME staged tile -> publish xp1(t-1) as seq-embedded u64 (fire&forget).
//  role1: L1 recurrence. Stage h1_t (flag-synced), mma W_hh1, THEN poll its 4 xp1
//         words (seq==t+1) -> tanh -> publish h1(t+1)+flag1.
// flag1 doubles as xp1-ring back-pressure for L0 (slack 7, lazy).
// W fragments are PINNED in VGPRs via asm keep-alive (round2/5 VGPR_Count=96..112
// proved the compiler was re-loading ~128KB/step of W from L2 inside the loop).
#define RLDA 520     // 512 + 8 pad (bf16)
#define RDEP 8

#define MMA16(ACC, WH, WL) do { \
    _Pragma("unroll") \
    for (int kt = 0; kt < 16; ++kt) { \
        bf16x8 ah = *(const bf16x8*)(&sAhi[lm*RLDA + kt*32 + q*8]); \
        bf16x8 al = *(const bf16x8*)(&sAlo[lm*RLDA + kt*32 + q*8]); \
        ACC = __builtin_amdgcn_mfma_f32_16x16x32_bf16(ah, WH[kt], ACC, 0,0,0); \
        ACC = __builtin_amdgcn_mfma_f32_16x16x32_bf16(ah, WL[kt], ACC, 0,0,0); \
        ACC = __builtin_amdgcn_mfma_f32_16x16x32_bf16(al, WH[kt], ACC, 0,0,0); \
    } } while (0)

__global__ __launch_bounds__(256, 1) void rnn_fused(
    const float* __restrict__ xp0,                       // [B,T,H] fp32 (gemm output)
    const __bf16* __restrict__ w0hi, const __bf16* __restrict__ w0lo,   // W_hh0 split
    const __bf16* __restrict__ wphi, const __bf16* __restrict__ wplo,   // W_ih1 split
    const __bf16* __restrict__ w1hi, const __bf16* __restrict__ w1lo,   // W_hh1 split
    const float* __restrict__ bias1,                     // bih1+bhh1
    unsigned* __restrict__ h0ring,                       // [8][B*H] packed u32, zeroed
    u64*      __restrict__ xp1ring,                      // [8][B*H] u64 seq|fp32, zeroed
    unsigned* __restrict__ h1ring,                       // [2][B*H] packed u32, zeroed
    float* __restrict__ hlast,                           // [B,H]
    int* __restrict__ flags)                             // [2][4][16], zeroed
{
    __shared__ __bf16 sAhi[16*RLDA], sAlo[16*RLDA];
    const int tid  = threadIdx.x;
    const int role = blockIdx.x >> 5;       // 0: L0+proj, 1: L1
    const int sub  = blockIdx.x & 31;
    const int g    = sub >> 3;              // batch group (16 rows)
    const int c    = sub & 7;               // column block (64 cols)
    const int m0g  = g * 16;
    const int n0   = c * 64;
    const int wave = tid >> 6, lane = tid & 63, lm = lane & 15, q = lane >> 4;
    const int ncol = n0 + wave*16 + lm;
    const int srow = tid >> 4, sseg = tid & 15;

    int* const flag0 = flags + g*16;        // L0 peers' progress
    int* const flag1 = flags + 64 + g*16;   // L1 progress (also xp1 back-pressure)

    // ---- W fragments, pinned in registers ----
    const __bf16* Wh = role ? w1hi : w0hi;
    const __bf16* Wl = role ? w1lo : w0lo;
    bf16x8 wh[16], wl[16], ph[16], pl[16];
#pragma unroll
    for (int kt = 0; kt < 16; ++kt) {
        wh[kt] = *(const bf16x8*)(&Wh[(size_t)ncol*H_ + kt*32 + q*8]);
        wl[kt] = *(const bf16x8*)(&Wl[(size_t)ncol*H_ + kt*32 + q*8]);
        asm volatile("" : "+v"(wh[kt]), "+v"(wl[kt]));   // forbid remat -> stay VGPR-resident
    }
    if (role == 0) {
#pragma unroll
        for (int kt = 0; kt < 16; ++kt) {
            ph[kt] = *(const bf16x8*)(&wphi[(size_t)ncol*H_ + kt*32 + q*8]);
            pl[kt] = *(const bf16x8*)(&wplo[(size_t)ncol*H_ + kt*32 + q*8]);
            asm volatile("" : "+v"(ph[kt]), "+v"(pl[kt]));
        }
    }

    // bulk stage: 16x512 packed u32 (as u64 pairs, agent-scope = L2-bypass) -> LDS planes
    auto stage = [&](const unsigned* base) {
        const u64* row = (const u64*)(base + (size_t)(m0g + srow)*H_);
        __bf16* dh = &sAhi[srow*RLDA];
        __bf16* dl = &sAlo[srow*RLDA];
        u64 vv[16];
#pragma unroll
        for (int j = 0; j < 16; ++j)
            vv[j] = __hip_atomic_load(&row[sseg + j*16], __ATOMIC_RELAXED,
                                      __HIP_MEMORY_SCOPE_AGENT);
#pragma unroll
        for (int j = 0; j < 16; ++j) {
            unsigned pa = (unsigned)vv[j], pb = (unsigned)(vv[j] >> 32);
            int c0 = (sseg + j*16) * 2;
            *(unsigned*)(dh + c0) = (pa >> 16) | (pb & 0xffff0000u);
            *(unsigned*)(dl + c0) = (pa & 0xffffu) | (pb << 16);
        }
    };
    // all-lane flag poll: lane i watches flag[i&7]; uniform exit per wave
    auto pollge = [&](int* f, int tv) {
        for (;;) {
            int v = __hip_atomic_load(&f[lane & 7], __ATOMIC_RELAXED,
                                      __HIP_MEMORY_SCOPE_AGENT);
            if (__all(v >= tv)) break;
            __builtin_amdgcn_s_sleep(1);
        }
    };

    if (role == 0) {
        // ---------------- layer-0 recurrence + inline projection ----------------
        const float b1 = bias1[ncol];
        for (int t = 0; t <= T_; ++t) {
            float xr[4];
            if (t < T_) {
#pragma unroll
                for (int r = 0; r < 4; ++r)
                    xr[r] = xp0[((size_t)(m0g + q*4 + r)*T_ + t)*H_ + ncol];
            }
            if (t) pollge(flag0, t);            // peers published h0(t)
            __syncthreads();                    // gate + LDS WAR (prev proj mma done)
            stage(h0ring + (size_t)(t & 7)*(B_*H_));
            __syncthreads();

            if (t < T_) {                       // recurrence (critical path first)
                f32x4 acc = (f32x4){0.f,0.f,0.f,0.f};
                MMA16(acc, wh, wl);
                unsigned* dst = h0ring + (size_t)((t+1) & 7)*(B_*H_);
#pragma unroll
                for (int r = 0; r < 4; ++r) {
                    float hv = tanhf(xr[r] + acc[r]);
                    __bf16 hh, hl; split_f32(hv, hh, hl);
                    unsigned pk = ((unsigned)__builtin_bit_cast(unsigned short, hh) << 16)
                                |  (unsigned)__builtin_bit_cast(unsigned short, hl);
                    __hip_atomic_store(&dst[(size_t)(m0g + q*4 + r)*H_ + ncol], pk,
                                       __ATOMIC_RELAXED, __HIP_MEMORY_SCOPE_AGENT);
                }
                __syncthreads();                // every thread's stores drained
                if (tid == 0)
                    __hip_atomic_store(&flag0[c], t+1, __ATOMIC_RELEASE,
                                       __HIP_MEMORY_SCOPE_AGENT);
            }
            if (t >= 1) {                       // proj of staged h0_t -> xp1(t-1), seq=t
                f32x4 a2 = (f32x4){0.f,0.f,0.f,0.f};
                MMA16(a2, ph, pl);
                if (t >= RDEP + 1)              // overwrite xp1(t-9): L1 must be past it
                    pollge(flag1, t - RDEP);
                u64* dst = xp1ring + (size_t)((t-1) & 7)*(B_*H_);
#pragma unroll
                for (int r = 0; r < 4; ++r) {
                    u64 pv = ((u64)(unsigned)t << 32) | __float_as_uint(a2[r] + b1);
                    __hip_atomic_store(&dst[(size_t)(m0g + q*4 + r)*H_ + ncol], pv,
                                       __ATOMIC_RELAXED, __HIP_MEMORY_SCOPE_AGENT);
                }
            }
        }
    } else {
        // ---------------- layer-1 recurrence ----------------
        for (int t = 0; t < T_; ++t) {
            // early first-attempt xp1 loads (checked after the mma)
            const u64* xs = xp1ring + (size_t)(t & 7)*(B_*H_);
            u64 xv[4];
#pragma unroll
            for (int r = 0; r < 4; ++r)
                xv[r] = __hip_atomic_load(&xs[(size_t)(m0g + q*4 + r)*H_ + ncol],
                                          __ATOMIC_RELAXED, __HIP_MEMORY_SCOPE_AGENT);
            if (t) pollge(flag1, t);            // peers published h1(t)
            __syncthreads();
            stage(h1ring + (size_t)(t & 1)*(B_*H_));
            __syncthreads();

            f32x4 acc = (f32x4){0.f,0.f,0.f,0.f};
            MMA16(acc, wh, wl);

            // finish xp1 poll (4 words/thread; usually already hit)
#pragma unroll
            for (int r = 0; r < 4; ++r) {
                while ((unsigned)(xv[r] >> 32) != (unsigned)(t+1)) {
                    __builtin_amdgcn_s_sleep(1);
                    xv[r] = __hip_atomic_load(&xs[(size_t)(m0g + q*4 + r)*H_ + ncol],
                                              __ATOMIC_RELAXED, __HIP_MEMORY_SCOPE_AGENT);
                }
            }
            unsigned* dst = h1ring + (size_t)((t+1) & 1)*(B_*H_);
#pragma unroll
            for (int r = 0; r < 4; ++r) {
                int m = m0g + q*4 + r;
                float hv = tanhf(__uint_as_float((unsigned)xv[r]) + acc[r]);
                __bf16 hh, hl; split_f32(hv, hh, hl);
                unsigned pk = ((unsigned)__builtin_bit_cast(unsigned short, hh) << 16)
                            |  (unsigned)__builtin_bit_cast(unsigned short, hl);
                __hip_atomic_store(&dst[(size_t)m*H_ + ncol], pk,
                                   __ATOMIC_RELAXED, __HIP_MEMORY_SCOPE_AGENT);
                if (t == T_-1) hlast[(size_t)m*H_ + ncol] = hv;
            }
            __syncthreads();                    // drain publishes (+ xp1 reads retired)
            if (tid == 0)
                __hip_atomic_store(&flag1[c], t+1, __ATOMIC_RELEASE,
                                   __HIP_MEMORY_SCOPE_AGENT);
        }
    }
}

// ---------------- output projection ----------------
__global__ __launch_bounds__(256) void out_proj(
    const float* __restrict__ hlast, const float* __restrict__ Wout,
    const float* __restrict__ bout, float* __restrict__ out)
{
    __shared__ float sh[H_];
    int b = blockIdx.x;
    for (int i = threadIdx.x; i < H_; i += 256) sh[i] = hlast[(size_t)b*H_ + i];
    __syncthreads();
    int o = threadIdx.x;
    const float* wr = &Wout[(size_t)o*H_];
    float acc = 0.f;
#pragma unroll 4
    for (int k = 0; k < H_; k += 4) {
        float4 wv = *(const float4*)(&wr[k]);
        acc += wv.x*sh[k] + wv.y*sh[k+1] + wv.z*sh[k+2] + wv.w*sh[k+3];
    }
    out[(size_t)b*OUT_ + o] = bout[o] + acc;
}

extern "C" void kernel_launch(void* const* d_in, const int* in_sizes, int n_in,
                              void* d_out, int out_size, void* d_ws, size_t ws_size,
                              hipStream_t stream)
{
    const float* x    = (const float*)d_in[0];
    const float* Wih0 = (const float*)d_in[1];
    const float* Whh0 = (const float*)d_in[2];
    const float* bih0 = (const float*)d_in[3];
    const float* bhh0 = (const float*)d_in[4];
    const float* Wih1 = (const float*)d_in[5];
    const float* Whh1 = (const float*)d_in[6];
    const float* bih1 = (const float*)d_in[7];
    const float* bhh1 = (const float*)d_in[8];
    const float* Wout = (const float*)d_in[9];
    const float* bout = (const float*)d_in[10];

    char* w = (char*)d_ws;
    size_t off = 0;
    auto alloc = [&](size_t bytes) -> void* {
        void* p = w + off; off = (off + bytes + 255) & ~(size_t)255; return p;
    };
    float*  xp     = (float*) alloc((size_t)M_*H_*4);      // 64 MB xp0 (read-only in fused)
    __bf16* wih0hi = (__bf16*)alloc((size_t)H_*IN_*2);
    __bf16* wih0lo = (__bf16*)alloc((size_t)H_*IN_*2);
    __bf16* whh0hi = (__bf16*)alloc((size_t)H_*H_*2);
    __bf16* whh0lo = (__bf16*)alloc((size_t)H_*H_*2);
    __bf16* wih1hi = (__bf16*)alloc((size_t)H_*H_*2);
    __bf16* wih1lo = (__bf16*)alloc((size_t)H_*H_*2);
    __bf16* whh1hi = (__bf16*)alloc((size_t)H_*H_*2);
    __bf16* whh1lo = (__bf16*)alloc((size_t)H_*H_*2);
    float*  bias0  = (float*) alloc(H_*4);
    float*  bias1  = (float*) alloc(H_*4);
    size_t zstart = off;                                   // zero-init region start
    unsigned* h0ring = (unsigned*)alloc((size_t)RDEP*B_*H_*4);  // 1 MB
    u64*      xp1ring= (u64*)     alloc((size_t)RDEP*B_*H_*8);  // 2 MB
    unsigned* h1ring = (unsigned*)alloc((size_t)2*B_*H_*4);     // 256 KB
    int*      flags  = (int*)     alloc(512);                   // [2][4][16]
    size_t zlen = off - zstart;
    float*  hlast  = (float*) alloc((size_t)B_*H_*4);

    // zero rings + flags (ws is poisoned before every launch; seq fields must start 0)
    hipMemsetAsync(w + zstart, 0, zlen, stream);

    // weight split + bias combine
    split_arr<<<(H_*IN_+255)/256, 256, 0, stream>>>(Wih0, wih0hi, wih0lo, H_*IN_);
    split_arr<<<(H_*H_ +255)/256, 256, 0, stream>>>(Whh0, whh0hi, whh0lo, H_*H_);
    split_arr<<<(H_*H_ +255)/256, 256, 0, stream>>>(Wih1, wih1hi, wih1lo, H_*H_);
    split_arr<<<(H_*H_ +255)/256, 256, 0, stream>>>(Whh1, whh1hi, whh1lo, H_*H_);
    bias_comb<<<2, 256, 0, stream>>>(bih0, bhh0, bias0, H_);
    bias_comb<<<2, 256, 0, stream>>>(bih1, bhh1, bias1, H_);

    // layer-0 input projection (one big GEMM, K=256)
    dim3 ggrid(H_/GBN, M_/GBM);  // (8, 256)
    gemm_xp<<<ggrid, 256, 0, stream>>>(x, wih0hi, wih0lo, bias0, xp, IN_);

    // fused 2-role pipelined recurrences (L0+proj -> L1)
    rnn_fused<<<64, 256, 0, stream>>>(xp, whh0hi, whh0lo, wih1hi, wih1lo,
                                      whh1hi, whh1lo, bias1,
                                      h0ring, xp1ring, h1ring, hlast, flags);

    // output projection
    out_proj<<<B_, 256, 0, stream>>>(hlast, Wout, bout, (float*)d_out);
}